// Round 1
// baseline (1177.801 us; speedup 1.0000x reference)
//
#include <hip/hip_runtime.h>
#include <math.h>

#define B_   4
#define H_   48
#define W_   48
#define DM_  192
#define DI_  384
#define L_   2304      // H_*W_
#define K_   4
#define DS_  16
#define DTR_ 12
#define C44  44        // DTR + 2*DS

// ---------------------------------------------------------------------------
// Generic batched NT GEMM: C[m,n] = sum_k A[m,k]*B[n,k]
// A: lda row-major, B: ldb row-major (N rows of K), C: ldc.
// Per-batch offsets: A += z*sA, B += (z%bmod)*sB, C += z*sC.
// EPI==1: v = softplus(v + bias[(z%bmod)*N + n])
// ---------------------------------------------------------------------------
#define BM 64
#define BN 64
#define BKT 16

template<int EPI>
__global__ __launch_bounds__(256) void gemm_nt(
    const float* __restrict__ Ag, const float* __restrict__ Bg,
    float* __restrict__ Cg, const float* __restrict__ biasg,
    int M, int N, int Kd, int lda, int ldb, int ldc,
    long sA, long sB, int bmod, long sC)
{
    const int batch = blockIdx.z;
    const float* A = Ag + (long)batch * sA;
    const float* Bm = Bg + (long)(batch % bmod) * sB;
    float* C = Cg + (long)batch * sC;
    const float* bias = (EPI == 1) ? (biasg + (long)(batch % bmod) * N) : nullptr;

    __shared__ float As[BKT][BM + 4];
    __shared__ float Bs[BKT][BN + 4];

    const int tid = threadIdx.x;
    const int tx = tid & 15;        // 0..15
    const int ty = tid >> 4;        // 0..15
    const int row0 = blockIdx.x * BM;
    const int col0 = blockIdx.y * BN;

    const int kc = tid & (BKT - 1); // 0..15
    const int rr = tid >> 4;        // 0..15

    float acc[4][4] = {};

    for (int k0 = 0; k0 < Kd; k0 += BKT) {
        #pragma unroll
        for (int p = 0; p < 4; ++p) {
            int r = rr + p * 16;
            int gk = k0 + kc;
            int gr = row0 + r;
            float va = 0.f;
            if (gr < M && gk < Kd) va = A[(long)gr * lda + gk];
            As[kc][r] = va;
            int gc = col0 + r;
            float vb = 0.f;
            if (gc < N && gk < Kd) vb = Bm[(long)gc * ldb + gk];
            Bs[kc][r] = vb;
        }
        __syncthreads();
        #pragma unroll
        for (int kk = 0; kk < BKT; ++kk) {
            float a[4], b[4];
            #pragma unroll
            for (int i = 0; i < 4; ++i) a[i] = As[kk][ty * 4 + i];
            #pragma unroll
            for (int j = 0; j < 4; ++j) b[j] = Bs[kk][tx * 4 + j];
            #pragma unroll
            for (int i = 0; i < 4; ++i)
                #pragma unroll
                for (int j = 0; j < 4; ++j)
                    acc[i][j] += a[i] * b[j];
        }
        __syncthreads();
    }

    #pragma unroll
    for (int i = 0; i < 4; ++i) {
        int gr = row0 + ty * 4 + i;
        if (gr >= M) continue;
        #pragma unroll
        for (int j = 0; j < 4; ++j) {
            int gc = col0 + tx * 4 + j;
            if (gc >= N) continue;
            float v = acc[i][j];
            if (EPI == 1) {
                v += bias[gc];
                v = (v > 20.f) ? v : log1pf(__expf(v));
            }
            C[(long)gr * ldc + gc] = v;
        }
    }
}

// ---------------------------------------------------------------------------
// Depthwise/grouped 3x3 convs + bias + SiLU.
// First half of threads: xc from xz (NHWC, 768 stride, first 384 chans),
// depthwise (group = channel). Second half: xtc from xt (NHWC 192),
// grouped: out channel c uses in channel c/2.
// ---------------------------------------------------------------------------
__global__ __launch_bounds__(256) void conv_dw(
    const float* __restrict__ xz, const float* __restrict__ xt,
    const float* __restrict__ w1, const float* __restrict__ b1,
    const float* __restrict__ w2, const float* __restrict__ b2,
    float* __restrict__ xc, float* __restrict__ xtc)
{
    const int total = B_ * H_ * W_ * DI_;
    int idx = blockIdx.x * blockDim.x + threadIdx.x;
    if (idx >= 2 * total) return;
    const bool second = idx >= total;
    int i = second ? idx - total : idx;
    const int c = i % DI_;
    int rest = i / DI_;
    const int w = rest % W_; rest /= W_;
    const int h = rest % H_;
    const int b = rest / H_;

    float acc;
    if (!second) {
        acc = b1[c];
        const float* wp = w1 + c * 9;
        #pragma unroll
        for (int dh = 0; dh < 3; ++dh) {
            int hh = h + dh - 1;
            if (hh < 0 || hh >= H_) continue;
            #pragma unroll
            for (int dw = 0; dw < 3; ++dw) {
                int ww = w + dw - 1;
                if (ww < 0 || ww >= W_) continue;
                acc += xz[((long)((b * H_ + hh) * W_ + ww)) * (2 * DI_) + c] * wp[dh * 3 + dw];
            }
        }
    } else {
        acc = b2[c];
        const int ci = c >> 1;
        const float* wp = w2 + c * 9;
        #pragma unroll
        for (int dh = 0; dh < 3; ++dh) {
            int hh = h + dh - 1;
            if (hh < 0 || hh >= H_) continue;
            #pragma unroll
            for (int dw = 0; dw < 3; ++dw) {
                int ww = w + dw - 1;
                if (ww < 0 || ww >= W_) continue;
                acc += xt[((long)((b * H_ + hh) * W_ + ww)) * DM_ + ci] * wp[dh * 3 + dw];
            }
        }
    }
    float v = acc / (1.f + __expf(-acc));   // SiLU
    (second ? xtc : xc)[i] = v;
}

// ---------------------------------------------------------------------------
// Build xs[B,4,L,DI] (d inner) from xc/xtc [B,H,W,DI]:
//  inter_row[h,w]: h even -> mean+max(xc[h],xc[h+1]); h odd -> (xtc[h-1],xtc[h])
//  inter_col[h,w]: w even -> mean+max(xc[w],xc[w+1]); w odd -> (xtc[w-1],xtc[w])
//  k=0: l=w*H+h <- ir ; k=1: l=w*H+(H-1-h) <- ir
//  k=2: l=h*W+w <- ic ; k=3: l=h*W+(W-1-w) <- ic
// ---------------------------------------------------------------------------
__global__ __launch_bounds__(256) void build_xs(
    const float* __restrict__ xc, const float* __restrict__ xtc,
    float* __restrict__ xs)
{
    const int total = B_ * H_ * W_ * DI_;
    int idx = blockIdx.x * blockDim.x + threadIdx.x;
    if (idx >= total) return;
    const int d = idx % DI_;
    int rest = idx / DI_;
    const int w = rest % W_; rest /= W_;
    const int h = rest % H_;
    const int b = rest / H_;

    long sp = (long)(b * H_ + h) * W_ + w;  // (b,h,w) flat
    float a, bb, ir, ic;
    // inter_row
    if ((h & 1) == 0) {
        a  = xc[((long)((b * H_ + h)     * W_ + w)) * DI_ + d];
        bb = xc[((long)((b * H_ + h + 1) * W_ + w)) * DI_ + d];
    } else {
        a  = xtc[((long)((b * H_ + h - 1) * W_ + w)) * DI_ + d];
        bb = xtc[((long)((b * H_ + h)     * W_ + w)) * DI_ + d];
    }
    ir = 0.5f * (a + bb) + fmaxf(a, bb);
    // inter_col
    if ((w & 1) == 0) {
        a  = xc[((long)((b * H_ + h) * W_ + w))     * DI_ + d];
        bb = xc[((long)((b * H_ + h) * W_ + w + 1)) * DI_ + d];
    } else {
        a  = xtc[((long)((b * H_ + h) * W_ + w - 1)) * DI_ + d];
        bb = xtc[((long)((b * H_ + h) * W_ + w))     * DI_ + d];
    }
    ic = 0.5f * (a + bb) + fmaxf(a, bb);

    long base = (long)b * K_ * L_ * DI_;
    xs[base + 0L * L_ * DI_ + (long)(w * H_ + h)            * DI_ + d] = ir;
    xs[base + 1L * L_ * DI_ + (long)(w * H_ + (H_ - 1 - h)) * DI_ + d] = ir;
    xs[base + 2L * L_ * DI_ + (long)(h * W_ + w)            * DI_ + d] = ic;
    xs[base + 3L * L_ * DI_ + (long)(h * W_ + (W_ - 1 - w)) * DI_ + d] = ic;
}

// ---------------------------------------------------------------------------
// Selective scan. Block = 16 d-channels x 16 state-lanes for one (b,k,dgroup).
// xs/delta: [B,K,L,DI]; xdbl: [B,K,L,44] (B at c=12..27, C at 28..43).
// outy: [B,K,L,DI].
// ---------------------------------------------------------------------------
__global__ __launch_bounds__(256) void scan_kernel(
    const float* __restrict__ xs, const float* __restrict__ delta,
    const float* __restrict__ xdbl, const float* __restrict__ A_logs,
    const float* __restrict__ Ds, float* __restrict__ outy)
{
    const int bid = blockIdx.x;           // B_*K_*(DI_/16) = 384
    const int dg = bid % (DI_ / 16);
    const int bk = bid / (DI_ / 16);      // b*K + k
    const int k = bk % K_;
    const int tid = threadIdx.x;
    const int ci = tid >> 4;              // channel in group: 0..15
    const int n  = tid & 15;              // state index
    const int d = dg * 16 + ci;

    const float An = -__expf(A_logs[(long)(k * DI_ + d) * DS_ + n]);
    const float Dv = Ds[k * DI_ + d];

    const float* xsp = xs    + (long)bk * L_ * DI_ + d;
    const float* dlp = delta + (long)bk * L_ * DI_ + d;
    const float* bp  = xdbl  + (long)bk * L_ * C44 + 12 + n;
    const float* cp  = xdbl  + (long)bk * L_ * C44 + 28 + n;
    float* yp = outy + (long)bk * L_ * DI_ + d;

    float s = 0.f;
    float dl = dlp[0], u = xsp[0], Bn = bp[0], Cn = cp[0];
    for (int l = 0; l < L_; ++l) {
        float dln = 0.f, un = 0.f, Bnn = 0.f, Cnn = 0.f;
        if (l + 1 < L_) {
            long o = (long)(l + 1);
            dln = dlp[o * DI_]; un = xsp[o * DI_];
            Bnn = bp[o * C44]; Cnn = cp[o * C44];
        }
        float dA = __expf(dl * An);
        s = s * dA + dl * Bn * u;
        float yv = s * Cn;
        yv += __shfl_xor(yv, 8, 16);
        yv += __shfl_xor(yv, 4, 16);
        yv += __shfl_xor(yv, 2, 16);
        yv += __shfl_xor(yv, 1, 16);
        if (n == 0) yp[(long)l * DI_] = yv + Dv * u;
        dl = dln; u = un; Bn = Bnn; Cn = Cnn;
    }
}

// ---------------------------------------------------------------------------
// Combine 4 scan directions + LayerNorm(384) + SiLU(z) gate.
// outy: [B,K,L,DI]; xz: [B*L, 768] (z = cols 384..767); yln: [B*L, DI].
// y[l=h*W+w,d] = outy[0][l] + outy[2][L-1-l] + outy[1][w*H+h] + outy[3][L-1-(w*H+h)]
// ---------------------------------------------------------------------------
__global__ __launch_bounds__(384) void combine_ln(
    const float* __restrict__ outy, const float* __restrict__ xz,
    const float* __restrict__ g, const float* __restrict__ bta,
    float* __restrict__ yln)
{
    const int bl = blockIdx.x;            // b*L + l
    const int b = bl / L_;
    const int l = bl % L_;
    const int h = l / W_;
    const int w = l % W_;
    const int d = threadIdx.x;

    const long base = (long)b * K_ * L_ * DI_;
    const int l1 = w * H_ + h;
    float v = outy[base + 0L * L_ * DI_ + (long)l            * DI_ + d]
            + outy[base + 2L * L_ * DI_ + (long)(L_ - 1 - l) * DI_ + d]
            + outy[base + 1L * L_ * DI_ + (long)l1           * DI_ + d]
            + outy[base + 3L * L_ * DI_ + (long)(L_ - 1 - l1)* DI_ + d];

    __shared__ float red[16];
    const int lane = d & 63, wid = d >> 6;

    float s = v;
    #pragma unroll
    for (int off = 32; off; off >>= 1) s += __shfl_down(s, off, 64);
    if (lane == 0) red[wid] = s;
    __syncthreads();
    if (d == 0) {
        float t = 0.f;
        for (int i = 0; i < 6; ++i) t += red[i];
        red[8] = t * (1.f / DI_);
    }
    __syncthreads();
    const float mu = red[8];
    float dv = v - mu;
    float s2 = dv * dv;
    #pragma unroll
    for (int off = 32; off; off >>= 1) s2 += __shfl_down(s2, off, 64);
    if (lane == 0) red[wid] = s2;
    __syncthreads();
    if (d == 0) {
        float t = 0.f;
        for (int i = 0; i < 6; ++i) t += red[i];
        red[9] = t * (1.f / DI_);
    }
    __syncthreads();
    const float var = red[9];

    float z = xz[(long)bl * (2 * DI_) + DI_ + d];
    float sz = z / (1.f + __expf(-z));
    float o = dv * rsqrtf(var + 1e-5f) * g[d] + bta[d];
    yln[(long)bl * DI_ + d] = o * sz;
}

// ---------------------------------------------------------------------------
extern "C" void kernel_launch(void* const* d_in, const int* in_sizes, int n_in,
                              void* d_out, int out_size, void* d_ws, size_t ws_size,
                              hipStream_t stream)
{
    const float* x    = (const float*)d_in[0];
    const float* xt   = (const float*)d_in[1];
    const float* ipw  = (const float*)d_in[2];
    const float* c2w  = (const float*)d_in[3];
    const float* c2b  = (const float*)d_in[4];
    const float* cxw  = (const float*)d_in[5];
    const float* cxb  = (const float*)d_in[6];
    const float* xpw  = (const float*)d_in[7];
    const float* dtw  = (const float*)d_in[8];
    const float* dtb  = (const float*)d_in[9];
    const float* alog = (const float*)d_in[10];
    const float* Dsp  = (const float*)d_in[11];
    const float* ng   = (const float*)d_in[12];
    const float* nb   = (const float*)d_in[13];
    const float* opw  = (const float*)d_in[14];
    float* out = (float*)d_out;

    const size_t M = (size_t)B_ * L_;          // 9216
    float* ws = (float*)d_ws;
    float* xz    = ws;                                   // [M,768]
    float* xc    = xz    + M * (2 * DI_);                // [B,H,W,DI]
    float* xtc   = xc    + M * DI_;                      // [B,H,W,DI]
    float* xs    = xtc   + M * DI_;                      // [B,4,L,DI]
    float* xdbl  = xs    + (size_t)B_ * K_ * L_ * DI_;   // [B,4,L,44]
    float* delta = xdbl  + (size_t)B_ * K_ * L_ * C44;   // [B,4,L,DI]
    float* outy  = delta + (size_t)B_ * K_ * L_ * DI_;   // [B,4,L,DI]
    float* yln   = xc;                                   // reuse (xc dead after build_xs)

    dim3 blk(256);

    // K1: xz = x @ in_proj_w^T   [9216,192] x [768,192]
    gemm_nt<0><<<dim3((int)(M / BM), (2 * DI_) / BN, 1), blk, 0, stream>>>(
        x, ipw, xz, nullptr, (int)M, 2 * DI_, DM_, DM_, DM_, 2 * DI_, 0, 0, 1, 0);

    // K2: convs + SiLU
    {
        int tot = 2 * B_ * H_ * W_ * DI_;
        conv_dw<<<(tot + 255) / 256, blk, 0, stream>>>(xz, xt, c2w, c2b, cxw, cxb, xc, xtc);
    }

    // K3: build xs
    {
        int tot = B_ * H_ * W_ * DI_;
        build_xs<<<(tot + 255) / 256, blk, 0, stream>>>(xc, xtc, xs);
    }

    // K4: x_dbl[b,k,l,c] = sum_d xs[b,k,l,d] * xpw[k,c,d]
    gemm_nt<0><<<dim3(L_ / BM, 1, B_ * K_), blk, 0, stream>>>(
        xs, xpw, xdbl, nullptr, L_, C44, DI_, DI_, DI_, C44,
        (long)L_ * DI_, (long)C44 * DI_, K_, (long)L_ * C44);

    // K5: delta[b,k,l,d] = softplus(sum_r x_dbl[b,k,l,r]*dtw[k,d,r] + bias[k,d])
    gemm_nt<1><<<dim3(L_ / BM, DI_ / BN, B_ * K_), blk, 0, stream>>>(
        xdbl, dtw, delta, dtb, L_, DI_, DTR_, C44, DTR_, DI_,
        (long)L_ * C44, (long)DI_ * DTR_, K_, (long)L_ * DI_);

    // K6: selective scan
    scan_kernel<<<B_ * K_ * (DI_ / 16), blk, 0, stream>>>(
        xs, delta, xdbl, alog, Dsp, outy);

    // K7: combine + LayerNorm + SiLU gate
    combine_ln<<<(int)M, 384, 0, stream>>>(outy, xz, ng, nb, yln);

    // K8: out = yln @ out_proj_w^T   [9216,384] x [192,384]
    gemm_nt<0><<<dim3((int)(M / BM), DM_ / BN, 1), blk, 0, stream>>>(
        yln, opw, out, nullptr, (int)M, DM_, DI_, DI_, DI_, DM_, 0, 0, 1, 0);
}

// Round 2
// 704.701 us; speedup vs baseline: 1.6713x; 1.6713x over previous
//
#include <hip/hip_runtime.h>
#include <math.h>

#define B_   4
#define H_   48
#define W_   48
#define DM_  192
#define DI_  384
#define L_   2304      // H_*W_
#define K_   4
#define DS_  16
#define DTR_ 12
#define C44  44        // DTR + 2*DS

// scan chunking
#define NC   16
#define CL   144                       // L_/NC
#define NSER (B_*K_*(DI_/16)*256)      // 98304 series (b,k,dg,ci,n)

// ---------------------------------------------------------------------------
// Generic batched NT GEMM: C[m,n] = sum_k A[m,k]*B[n,k]
// ---------------------------------------------------------------------------
#define BM 64
#define BN 64
#define BKT 16

template<int EPI>
__global__ __launch_bounds__(256) void gemm_nt(
    const float* __restrict__ Ag, const float* __restrict__ Bg,
    float* __restrict__ Cg, const float* __restrict__ biasg,
    int M, int N, int Kd, int lda, int ldb, int ldc,
    long sA, long sB, int bmod, long sC)
{
    const int batch = blockIdx.z;
    const float* A = Ag + (long)batch * sA;
    const float* Bm = Bg + (long)(batch % bmod) * sB;
    float* C = Cg + (long)batch * sC;
    const float* bias = (EPI == 1) ? (biasg + (long)(batch % bmod) * N) : nullptr;

    __shared__ float As[BKT][BM + 4];
    __shared__ float Bs[BKT][BN + 4];

    const int tid = threadIdx.x;
    const int tx = tid & 15;
    const int ty = tid >> 4;
    const int row0 = blockIdx.x * BM;
    const int col0 = blockIdx.y * BN;

    const int kc = tid & (BKT - 1);
    const int rr = tid >> 4;

    float acc[4][4] = {};

    for (int k0 = 0; k0 < Kd; k0 += BKT) {
        #pragma unroll
        for (int p = 0; p < 4; ++p) {
            int r = rr + p * 16;
            int gk = k0 + kc;
            int gr = row0 + r;
            float va = 0.f;
            if (gr < M && gk < Kd) va = A[(long)gr * lda + gk];
            As[kc][r] = va;
            int gc = col0 + r;
            float vb = 0.f;
            if (gc < N && gk < Kd) vb = Bm[(long)gc * ldb + gk];
            Bs[kc][r] = vb;
        }
        __syncthreads();
        #pragma unroll
        for (int kk = 0; kk < BKT; ++kk) {
            float a[4], b[4];
            #pragma unroll
            for (int i = 0; i < 4; ++i) a[i] = As[kk][ty * 4 + i];
            #pragma unroll
            for (int j = 0; j < 4; ++j) b[j] = Bs[kk][tx * 4 + j];
            #pragma unroll
            for (int i = 0; i < 4; ++i)
                #pragma unroll
                for (int j = 0; j < 4; ++j)
                    acc[i][j] += a[i] * b[j];
        }
        __syncthreads();
    }

    #pragma unroll
    for (int i = 0; i < 4; ++i) {
        int gr = row0 + ty * 4 + i;
        if (gr >= M) continue;
        #pragma unroll
        for (int j = 0; j < 4; ++j) {
            int gc = col0 + tx * 4 + j;
            if (gc >= N) continue;
            float v = acc[i][j];
            if (EPI == 1) {
                v += bias[gc];
                v = (v > 20.f) ? v : log1pf(__expf(v));
            }
            C[(long)gr * ldc + gc] = v;
        }
    }
}

// ---------------------------------------------------------------------------
// Depthwise/grouped 3x3 convs + bias + SiLU.
// ---------------------------------------------------------------------------
__global__ __launch_bounds__(256) void conv_dw(
    const float* __restrict__ xz, const float* __restrict__ xt,
    const float* __restrict__ w1, const float* __restrict__ b1,
    const float* __restrict__ w2, const float* __restrict__ b2,
    float* __restrict__ xc, float* __restrict__ xtc)
{
    const int total = B_ * H_ * W_ * DI_;
    int idx = blockIdx.x * blockDim.x + threadIdx.x;
    if (idx >= 2 * total) return;
    const bool second = idx >= total;
    int i = second ? idx - total : idx;
    const int c = i % DI_;
    int rest = i / DI_;
    const int w = rest % W_; rest /= W_;
    const int h = rest % H_;
    const int b = rest / H_;

    float acc;
    if (!second) {
        acc = b1[c];
        const float* wp = w1 + c * 9;
        #pragma unroll
        for (int dh = 0; dh < 3; ++dh) {
            int hh = h + dh - 1;
            if (hh < 0 || hh >= H_) continue;
            #pragma unroll
            for (int dw = 0; dw < 3; ++dw) {
                int ww = w + dw - 1;
                if (ww < 0 || ww >= W_) continue;
                acc += xz[((long)((b * H_ + hh) * W_ + ww)) * (2 * DI_) + c] * wp[dh * 3 + dw];
            }
        }
    } else {
        acc = b2[c];
        const int ci = c >> 1;
        const float* wp = w2 + c * 9;
        #pragma unroll
        for (int dh = 0; dh < 3; ++dh) {
            int hh = h + dh - 1;
            if (hh < 0 || hh >= H_) continue;
            #pragma unroll
            for (int dw = 0; dw < 3; ++dw) {
                int ww = w + dw - 1;
                if (ww < 0 || ww >= W_) continue;
                acc += xt[((long)((b * H_ + hh) * W_ + ww)) * DM_ + ci] * wp[dh * 3 + dw];
            }
        }
    }
    float v = acc / (1.f + __expf(-acc));   // SiLU
    (second ? xtc : xc)[i] = v;
}

// ---------------------------------------------------------------------------
// Build xs[B,4,L,DI]
// ---------------------------------------------------------------------------
__global__ __launch_bounds__(256) void build_xs(
    const float* __restrict__ xc, const float* __restrict__ xtc,
    float* __restrict__ xs)
{
    const int total = B_ * H_ * W_ * DI_;
    int idx = blockIdx.x * blockDim.x + threadIdx.x;
    if (idx >= total) return;
    const int d = idx % DI_;
    int rest = idx / DI_;
    const int w = rest % W_; rest /= W_;
    const int h = rest % H_;
    const int b = rest / H_;

    float a, bb, ir, ic;
    if ((h & 1) == 0) {
        a  = xc[((long)((b * H_ + h)     * W_ + w)) * DI_ + d];
        bb = xc[((long)((b * H_ + h + 1) * W_ + w)) * DI_ + d];
    } else {
        a  = xtc[((long)((b * H_ + h - 1) * W_ + w)) * DI_ + d];
        bb = xtc[((long)((b * H_ + h)     * W_ + w)) * DI_ + d];
    }
    ir = 0.5f * (a + bb) + fmaxf(a, bb);
    if ((w & 1) == 0) {
        a  = xc[((long)((b * H_ + h) * W_ + w))     * DI_ + d];
        bb = xc[((long)((b * H_ + h) * W_ + w + 1)) * DI_ + d];
    } else {
        a  = xtc[((long)((b * H_ + h) * W_ + w - 1)) * DI_ + d];
        bb = xtc[((long)((b * H_ + h) * W_ + w))     * DI_ + d];
    }
    ic = 0.5f * (a + bb) + fmaxf(a, bb);

    long base = (long)b * K_ * L_ * DI_;
    xs[base + 0L * L_ * DI_ + (long)(w * H_ + h)            * DI_ + d] = ir;
    xs[base + 1L * L_ * DI_ + (long)(w * H_ + (H_ - 1 - h)) * DI_ + d] = ir;
    xs[base + 2L * L_ * DI_ + (long)(h * W_ + w)            * DI_ + d] = ic;
    xs[base + 3L * L_ * DI_ + (long)(h * W_ + (W_ - 1 - w)) * DI_ + d] = ic;
}

// ---------------------------------------------------------------------------
// Chunked selective scan, 3 passes.
// Block = 16 d-channels x 16 state-lanes for one (b,k,dgroup,chunk).
// Series id: sid = ((bk*24 + dg)*256 + tid). Carry layout: [chunk][sid].
// ---------------------------------------------------------------------------
__global__ __launch_bounds__(256) void scan_p1(
    const float* __restrict__ xs, const float* __restrict__ delta,
    const float* __restrict__ xdbl, const float* __restrict__ A_logs,
    float* __restrict__ carryS, float* __restrict__ carryP)
{
    const int bid = blockIdx.x;               // (bk,dg)*(NC-1) + chunk
    const int chunk = bid % (NC - 1);
    int t = bid / (NC - 1);
    const int dg = t % (DI_ / 16);
    const int bk = t / (DI_ / 16);
    const int k = bk % K_;
    const int tid = threadIdx.x;
    const int ci = tid >> 4;
    const int n  = tid & 15;
    const int d = dg * 16 + ci;
    const int sid = (bk * (DI_ / 16) + dg) * 256 + tid;

    const float An = -__expf(A_logs[(long)(k * DI_ + d) * DS_ + n]);

    const long l0 = (long)chunk * CL;
    const float* xsp = xs    + (long)bk * L_ * DI_ + l0 * DI_ + d;
    const float* dlp = delta + (long)bk * L_ * DI_ + l0 * DI_ + d;
    const float* bp  = xdbl  + (long)bk * L_ * C44 + l0 * C44 + 12 + n;

    float s = 0.f, P = 1.f;
    for (int l = 0; l < CL; ++l) {
        float dl = dlp[(long)l * DI_];
        float u  = xsp[(long)l * DI_];
        float Bn = bp[(long)l * C44];
        float dA = __expf(dl * An);
        s = s * dA + dl * Bn * u;
        P *= dA;
    }
    carryS[(long)chunk * NSER + sid] = s;
    carryP[(long)chunk * NSER + sid] = P;
}

__global__ __launch_bounds__(256) void scan_p2(
    const float* __restrict__ carryS, const float* __restrict__ carryP,
    float* __restrict__ Sin)
{
    const int sid = blockIdx.x * 256 + threadIdx.x;   // NSER threads
    float s = 0.f;
    Sin[sid] = 0.f;
    #pragma unroll
    for (int c = 1; c < NC; ++c) {
        s = carryP[(long)(c - 1) * NSER + sid] * s + carryS[(long)(c - 1) * NSER + sid];
        Sin[(long)c * NSER + sid] = s;
    }
}

__global__ __launch_bounds__(256) void scan_p3(
    const float* __restrict__ xs, const float* __restrict__ delta,
    const float* __restrict__ xdbl, const float* __restrict__ A_logs,
    const float* __restrict__ Ds, const float* __restrict__ Sin,
    float* __restrict__ outy)
{
    const int bid = blockIdx.x;               // (bk,dg)*NC + chunk
    const int chunk = bid % NC;
    int t = bid / NC;
    const int dg = t % (DI_ / 16);
    const int bk = t / (DI_ / 16);
    const int k = bk % K_;
    const int tid = threadIdx.x;
    const int ci = tid >> 4;
    const int n  = tid & 15;
    const int d = dg * 16 + ci;
    const int sid = (bk * (DI_ / 16) + dg) * 256 + tid;

    const float An = -__expf(A_logs[(long)(k * DI_ + d) * DS_ + n]);
    const float Dv = Ds[k * DI_ + d];

    const long l0 = (long)chunk * CL;
    const float* xsp = xs    + (long)bk * L_ * DI_ + l0 * DI_ + d;
    const float* dlp = delta + (long)bk * L_ * DI_ + l0 * DI_ + d;
    const float* bp  = xdbl  + (long)bk * L_ * C44 + l0 * C44 + 12 + n;
    const float* cp  = xdbl  + (long)bk * L_ * C44 + l0 * C44 + 28 + n;
    float* yp = outy + (long)bk * L_ * DI_ + l0 * DI_ + d;

    float s = Sin[(long)chunk * NSER + sid];

    float dl = dlp[0], u = xsp[0], Bn = bp[0], Cn = cp[0];
    for (int l = 0; l < CL; ++l) {
        float dln = 0.f, un = 0.f, Bnn = 0.f, Cnn = 0.f;
        if (l + 1 < CL) {
            long o = (long)(l + 1);
            dln = dlp[o * DI_]; un = xsp[o * DI_];
            Bnn = bp[o * C44]; Cnn = cp[o * C44];
        }
        float dA = __expf(dl * An);
        s = s * dA + dl * Bn * u;
        float yv = s * Cn;
        yv += __shfl_xor(yv, 8, 16);
        yv += __shfl_xor(yv, 4, 16);
        yv += __shfl_xor(yv, 2, 16);
        yv += __shfl_xor(yv, 1, 16);
        if (n == 0) yp[(long)l * DI_] = yv + Dv * u;
        dl = dln; u = un; Bn = Bnn; Cn = Cnn;
    }
}

// ---------------------------------------------------------------------------
// Combine 4 scan directions + LayerNorm(384) + SiLU(z) gate.
// ---------------------------------------------------------------------------
__global__ __launch_bounds__(384) void combine_ln(
    const float* __restrict__ outy, const float* __restrict__ xz,
    const float* __restrict__ g, const float* __restrict__ bta,
    float* __restrict__ yln)
{
    const int bl = blockIdx.x;
    const int b = bl / L_;
    const int l = bl % L_;
    const int h = l / W_;
    const int w = l % W_;
    const int d = threadIdx.x;

    const long base = (long)b * K_ * L_ * DI_;
    const int l1 = w * H_ + h;
    float v = outy[base + 0L * L_ * DI_ + (long)l            * DI_ + d]
            + outy[base + 2L * L_ * DI_ + (long)(L_ - 1 - l) * DI_ + d]
            + outy[base + 1L * L_ * DI_ + (long)l1           * DI_ + d]
            + outy[base + 3L * L_ * DI_ + (long)(L_ - 1 - l1)* DI_ + d];

    __shared__ float red[16];
    const int lane = d & 63, wid = d >> 6;

    float s = v;
    #pragma unroll
    for (int off = 32; off; off >>= 1) s += __shfl_down(s, off, 64);
    if (lane == 0) red[wid] = s;
    __syncthreads();
    if (d == 0) {
        float t = 0.f;
        for (int i = 0; i < 6; ++i) t += red[i];
        red[8] = t * (1.f / DI_);
    }
    __syncthreads();
    const float mu = red[8];
    float dv = v - mu;
    float s2 = dv * dv;
    #pragma unroll
    for (int off = 32; off; off >>= 1) s2 += __shfl_down(s2, off, 64);
    if (lane == 0) red[wid] = s2;
    __syncthreads();
    if (d == 0) {
        float t = 0.f;
        for (int i = 0; i < 6; ++i) t += red[i];
        red[9] = t * (1.f / DI_);
    }
    __syncthreads();
    const float var = red[9];

    float z = xz[(long)bl * (2 * DI_) + DI_ + d];
    float sz = z / (1.f + __expf(-z));
    float o = dv * rsqrtf(var + 1e-5f) * g[d] + bta[d];
    yln[(long)bl * DI_ + d] = o * sz;
}

// ---------------------------------------------------------------------------
extern "C" void kernel_launch(void* const* d_in, const int* in_sizes, int n_in,
                              void* d_out, int out_size, void* d_ws, size_t ws_size,
                              hipStream_t stream)
{
    const float* x    = (const float*)d_in[0];
    const float* xt   = (const float*)d_in[1];
    const float* ipw  = (const float*)d_in[2];
    const float* c2w  = (const float*)d_in[3];
    const float* c2b  = (const float*)d_in[4];
    const float* cxw  = (const float*)d_in[5];
    const float* cxb  = (const float*)d_in[6];
    const float* xpw  = (const float*)d_in[7];
    const float* dtw  = (const float*)d_in[8];
    const float* dtb  = (const float*)d_in[9];
    const float* alog = (const float*)d_in[10];
    const float* Dsp  = (const float*)d_in[11];
    const float* ng   = (const float*)d_in[12];
    const float* nb   = (const float*)d_in[13];
    const float* opw  = (const float*)d_in[14];
    float* out = (float*)d_out;

    const size_t M = (size_t)B_ * L_;          // 9216
    float* ws = (float*)d_ws;
    float* xz    = ws;                                   // [M,768]
    float* xc    = xz    + M * (2 * DI_);                // [B,H,W,DI]
    float* xtc   = xc    + M * DI_;                      // [B,H,W,DI]
    float* xs    = xtc   + M * DI_;                      // [B,4,L,DI]
    float* xdbl  = xs    + (size_t)B_ * K_ * L_ * DI_;   // [B,4,L,44]
    float* delta = xdbl  + (size_t)B_ * K_ * L_ * C44;   // [B,4,L,DI]
    float* outy  = delta + (size_t)B_ * K_ * L_ * DI_;   // [B,4,L,DI]
    // scan carries overlay xc+xtc (dead between build_xs and combine_ln)
    float* carryS = xc;                                  // [NC][NSER]
    float* carryP = carryS + (size_t)NC * NSER;
    float* Sin    = carryP + (size_t)NC * NSER;
    float* yln   = xc;                                   // reused after scan

    dim3 blk(256);

    // K1: xz = x @ in_proj_w^T
    gemm_nt<0><<<dim3((int)(M / BM), (2 * DI_) / BN, 1), blk, 0, stream>>>(
        x, ipw, xz, nullptr, (int)M, 2 * DI_, DM_, DM_, DM_, 2 * DI_, 0, 0, 1, 0);

    // K2: convs + SiLU
    {
        int tot = 2 * B_ * H_ * W_ * DI_;
        conv_dw<<<(tot + 255) / 256, blk, 0, stream>>>(xz, xt, c2w, c2b, cxw, cxb, xc, xtc);
    }

    // K3: build xs
    {
        int tot = B_ * H_ * W_ * DI_;
        build_xs<<<(tot + 255) / 256, blk, 0, stream>>>(xc, xtc, xs);
    }

    // K4: x_dbl = xs @ xpw^T (batched over b,k)
    gemm_nt<0><<<dim3(L_ / BM, 1, B_ * K_), blk, 0, stream>>>(
        xs, xpw, xdbl, nullptr, L_, C44, DI_, DI_, DI_, C44,
        (long)L_ * DI_, (long)C44 * DI_, K_, (long)L_ * C44);

    // K5: delta = softplus(x_dbl[:, :12] @ dtw^T + bias)
    gemm_nt<1><<<dim3(L_ / BM, DI_ / BN, B_ * K_), blk, 0, stream>>>(
        xdbl, dtw, delta, dtb, L_, DI_, DTR_, C44, DTR_, DI_,
        (long)L_ * C44, (long)DI_ * DTR_, K_, (long)L_ * DI_);

    // K6: chunked selective scan (3 passes)
    scan_p1<<<B_ * K_ * (DI_ / 16) * (NC - 1), blk, 0, stream>>>(
        xs, delta, xdbl, alog, carryS, carryP);
    scan_p2<<<NSER / 256, blk, 0, stream>>>(carryS, carryP, Sin);
    scan_p3<<<B_ * K_ * (DI_ / 16) * NC, blk, 0, stream>>>(
        xs, delta, xdbl, alog, Dsp, Sin, outy);

    // K7: combine + LayerNorm + SiLU gate
    combine_ln<<<(int)M, 384, 0, stream>>>(outy, xz, ng, nb, yln);

    // K8: out = yln @ out_proj_w^T
    gemm_nt<0><<<dim3((int)(M / BM), DM_ / BN, 1), blk, 0, stream>>>(
        yln, opw, out, nullptr, (int)M, DM_, DI_, DI_, DI_, DM_, 0, 0, 1, 0);
}

// Round 3
// 536.941 us; speedup vs baseline: 2.1935x; 1.3124x over previous
//
#include <hip/hip_runtime.h>
#include <math.h>

#define B_   4
#define H_   48
#define W_   48
#define DM_  192
#define DI_  384
#define L_   2304      // H_*W_
#define K_   4
#define DS_  16
#define DTR_ 12
#define C44  44        // DTR + 2*DS

// scan chunking
#define NC   32
#define CL   72                        // L_/NC
#define NSER (B_*K_*DI_*DS_)           // 98304 series (b,k,d,n)

// ---------------------------------------------------------------------------
// Generic batched NT GEMM: C[m,n] = sum_k A[m,k]*B[n,k]
// ---------------------------------------------------------------------------
#define BM 64
#define BN 64
#define BKT 16

template<int EPI>
__global__ __launch_bounds__(256) void gemm_nt(
    const float* __restrict__ Ag, const float* __restrict__ Bg,
    float* __restrict__ Cg, const float* __restrict__ biasg,
    int M, int N, int Kd, int lda, int ldb, int ldc,
    long sA, long sB, int bmod, long sC)
{
    const int batch = blockIdx.z;
    const float* A = Ag + (long)batch * sA;
    const float* Bm = Bg + (long)(batch % bmod) * sB;
    float* C = Cg + (long)batch * sC;
    const float* bias = (EPI == 1) ? (biasg + (long)(batch % bmod) * N) : nullptr;

    __shared__ float As[BKT][BM + 4];
    __shared__ float Bs[BKT][BN + 4];

    const int tid = threadIdx.x;
    const int tx = tid & 15;
    const int ty = tid >> 4;
    const int row0 = blockIdx.x * BM;
    const int col0 = blockIdx.y * BN;

    const int kc = tid & (BKT - 1);
    const int rr = tid >> 4;

    float acc[4][4] = {};

    for (int k0 = 0; k0 < Kd; k0 += BKT) {
        #pragma unroll
        for (int p = 0; p < 4; ++p) {
            int r = rr + p * 16;
            int gk = k0 + kc;
            int gr = row0 + r;
            float va = 0.f;
            if (gr < M && gk < Kd) va = A[(long)gr * lda + gk];
            As[kc][r] = va;
            int gc = col0 + r;
            float vb = 0.f;
            if (gc < N && gk < Kd) vb = Bm[(long)gc * ldb + gk];
            Bs[kc][r] = vb;
        }
        __syncthreads();
        #pragma unroll
        for (int kk = 0; kk < BKT; ++kk) {
            float a[4], b[4];
            #pragma unroll
            for (int i = 0; i < 4; ++i) a[i] = As[kk][ty * 4 + i];
            #pragma unroll
            for (int j = 0; j < 4; ++j) b[j] = Bs[kk][tx * 4 + j];
            #pragma unroll
            for (int i = 0; i < 4; ++i)
                #pragma unroll
                for (int j = 0; j < 4; ++j)
                    acc[i][j] += a[i] * b[j];
        }
        __syncthreads();
    }

    #pragma unroll
    for (int i = 0; i < 4; ++i) {
        int gr = row0 + ty * 4 + i;
        if (gr >= M) continue;
        #pragma unroll
        for (int j = 0; j < 4; ++j) {
            int gc = col0 + tx * 4 + j;
            if (gc >= N) continue;
            float v = acc[i][j];
            if (EPI == 1) {
                v += bias[gc];
                v = (v > 20.f) ? v : log1pf(__expf(v));
            }
            C[(long)gr * ldc + gc] = v;
        }
    }
}

// ---------------------------------------------------------------------------
// Depthwise/grouped 3x3 convs + bias + SiLU.
// ---------------------------------------------------------------------------
__global__ __launch_bounds__(256) void conv_dw(
    const float* __restrict__ xz, const float* __restrict__ xt,
    const float* __restrict__ w1, const float* __restrict__ b1,
    const float* __restrict__ w2, const float* __restrict__ b2,
    float* __restrict__ xc, float* __restrict__ xtc)
{
    const int total = B_ * H_ * W_ * DI_;
    int idx = blockIdx.x * blockDim.x + threadIdx.x;
    if (idx >= 2 * total) return;
    const bool second = idx >= total;
    int i = second ? idx - total : idx;
    const int c = i % DI_;
    int rest = i / DI_;
    const int w = rest % W_; rest /= W_;
    const int h = rest % H_;
    const int b = rest / H_;

    float acc;
    if (!second) {
        acc = b1[c];
        const float* wp = w1 + c * 9;
        #pragma unroll
        for (int dh = 0; dh < 3; ++dh) {
            int hh = h + dh - 1;
            if (hh < 0 || hh >= H_) continue;
            #pragma unroll
            for (int dw = 0; dw < 3; ++dw) {
                int ww = w + dw - 1;
                if (ww < 0 || ww >= W_) continue;
                acc += xz[((long)((b * H_ + hh) * W_ + ww)) * (2 * DI_) + c] * wp[dh * 3 + dw];
            }
        }
    } else {
        acc = b2[c];
        const int ci = c >> 1;
        const float* wp = w2 + c * 9;
        #pragma unroll
        for (int dh = 0; dh < 3; ++dh) {
            int hh = h + dh - 1;
            if (hh < 0 || hh >= H_) continue;
            #pragma unroll
            for (int dw = 0; dw < 3; ++dw) {
                int ww = w + dw - 1;
                if (ww < 0 || ww >= W_) continue;
                acc += xt[((long)((b * H_ + hh) * W_ + ww)) * DM_ + ci] * wp[dh * 3 + dw];
            }
        }
    }
    float v = acc / (1.f + __expf(-acc));   // SiLU
    (second ? xtc : xc)[i] = v;
}

// ---------------------------------------------------------------------------
// Build xs[B,4,L,DI]
// ---------------------------------------------------------------------------
__global__ __launch_bounds__(256) void build_xs(
    const float* __restrict__ xc, const float* __restrict__ xtc,
    float* __restrict__ xs)
{
    const int total = B_ * H_ * W_ * DI_;
    int idx = blockIdx.x * blockDim.x + threadIdx.x;
    if (idx >= total) return;
    const int d = idx % DI_;
    int rest = idx / DI_;
    const int w = rest % W_; rest /= W_;
    const int h = rest % H_;
    const int b = rest / H_;

    float a, bb, ir, ic;
    if ((h & 1) == 0) {
        a  = xc[((long)((b * H_ + h)     * W_ + w)) * DI_ + d];
        bb = xc[((long)((b * H_ + h + 1) * W_ + w)) * DI_ + d];
    } else {
        a  = xtc[((long)((b * H_ + h - 1) * W_ + w)) * DI_ + d];
        bb = xtc[((long)((b * H_ + h)     * W_ + w)) * DI_ + d];
    }
    ir = 0.5f * (a + bb) + fmaxf(a, bb);
    if ((w & 1) == 0) {
        a  = xc[((long)((b * H_ + h) * W_ + w))     * DI_ + d];
        bb = xc[((long)((b * H_ + h) * W_ + w + 1)) * DI_ + d];
    } else {
        a  = xtc[((long)((b * H_ + h) * W_ + w - 1)) * DI_ + d];
        bb = xtc[((long)((b * H_ + h) * W_ + w))     * DI_ + d];
    }
    ic = 0.5f * (a + bb) + fmaxf(a, bb);

    long base = (long)b * K_ * L_ * DI_;
    xs[base + 0L * L_ * DI_ + (long)(w * H_ + h)            * DI_ + d] = ir;
    xs[base + 1L * L_ * DI_ + (long)(w * H_ + (H_ - 1 - h)) * DI_ + d] = ir;
    xs[base + 2L * L_ * DI_ + (long)(h * W_ + w)            * DI_ + d] = ic;
    xs[base + 3L * L_ * DI_ + (long)(h * W_ + (W_ - 1 - w)) * DI_ + d] = ic;
}

// ---------------------------------------------------------------------------
// Chunked selective scan, 3 passes. One thread per d-channel, 16 states in
// VGPRs, no cross-lane ops. Block = 384 threads = one (b,k,chunk).
// Carry layout: [chunk][(bk*DI+d)*16+n].
// ---------------------------------------------------------------------------
__global__ __launch_bounds__(384) void scan_p1(
    const float* __restrict__ xs, const float* __restrict__ delta,
    const float* __restrict__ xdbl, const float* __restrict__ A_logs,
    float* __restrict__ carryS, float* __restrict__ carryP)
{
    const int chunk = blockIdx.x % (NC - 1);
    const int bk = blockIdx.x / (NC - 1);
    const int k = bk % K_;
    const int d = threadIdx.x;

    float An[16];
    #pragma unroll
    for (int n = 0; n < 16; ++n)
        An[n] = -__expf(A_logs[(long)(k * DI_ + d) * DS_ + n]);

    const long l0 = (long)chunk * CL;
    const float* xsp = xs    + (long)bk * L_ * DI_ + l0 * DI_ + d;
    const float* dlp = delta + (long)bk * L_ * DI_ + l0 * DI_ + d;
    const float* bbase = xdbl + (long)bk * L_ * C44 + l0 * C44 + 12;

    float s[16];
    #pragma unroll
    for (int n = 0; n < 16; ++n) s[n] = 0.f;
    float sdl = 0.f;

    float dl = dlp[0], u = xsp[0];
    float4 b0 = ((const float4*)bbase)[0];
    float4 b1 = ((const float4*)bbase)[1];
    float4 b2 = ((const float4*)bbase)[2];
    float4 b3 = ((const float4*)bbase)[3];

    for (int l = 0; l < CL; ++l) {
        float dln = 0.f, un = 0.f;
        float4 nb0 = {}, nb1 = {}, nb2 = {}, nb3 = {};
        if (l + 1 < CL) {
            long o = (long)(l + 1);
            dln = dlp[o * DI_]; un = xsp[o * DI_];
            const float4* Bv = (const float4*)(bbase + o * C44);
            nb0 = Bv[0]; nb1 = Bv[1]; nb2 = Bv[2]; nb3 = Bv[3];
        }
        float B[16];
        *(float4*)&B[0] = b0; *(float4*)&B[4] = b1;
        *(float4*)&B[8] = b2; *(float4*)&B[12] = b3;
        const float du = dl * u;
        sdl += dl;
        #pragma unroll
        for (int n = 0; n < 16; ++n)
            s[n] = s[n] * __expf(dl * An[n]) + du * B[n];
        dl = dln; u = un; b0 = nb0; b1 = nb1; b2 = nb2; b3 = nb3;
    }

    const long sidb = ((long)bk * DI_ + d) * 16;
    float* cs = carryS + (long)chunk * NSER + sidb;
    float* cpp = carryP + (long)chunk * NSER + sidb;
    #pragma unroll
    for (int q = 0; q < 4; ++q) {
        float4 v; v.x = s[q*4]; v.y = s[q*4+1]; v.z = s[q*4+2]; v.w = s[q*4+3];
        ((float4*)cs)[q] = v;
        float4 p;
        p.x = __expf(An[q*4+0] * sdl); p.y = __expf(An[q*4+1] * sdl);
        p.z = __expf(An[q*4+2] * sdl); p.w = __expf(An[q*4+3] * sdl);
        ((float4*)cpp)[q] = p;
    }
}

// sequential combine across chunks, in place: after this, carryS[c-1] holds
// the incoming state for chunk c (chunk 0 incoming = 0).
__global__ __launch_bounds__(256) void scan_p2(
    float* __restrict__ carryS, const float* __restrict__ carryP)
{
    const int sid = blockIdx.x * 256 + threadIdx.x;
    float s = 0.f;
    #pragma unroll
    for (int c = 1; c < NC; ++c) {
        float Sv = carryS[(long)(c - 1) * NSER + sid];
        float Pv = carryP[(long)(c - 1) * NSER + sid];
        s = Pv * s + Sv;
        carryS[(long)(c - 1) * NSER + sid] = s;
    }
}

__global__ __launch_bounds__(384) void scan_p3(
    const float* __restrict__ xs, const float* __restrict__ delta,
    const float* __restrict__ xdbl, const float* __restrict__ A_logs,
    const float* __restrict__ Ds, const float* __restrict__ carryS,
    float* __restrict__ outy)
{
    const int chunk = blockIdx.x % NC;
    const int bk = blockIdx.x / NC;
    const int k = bk % K_;
    const int d = threadIdx.x;

    float An[16];
    #pragma unroll
    for (int n = 0; n < 16; ++n)
        An[n] = -__expf(A_logs[(long)(k * DI_ + d) * DS_ + n]);
    const float Dv = Ds[k * DI_ + d];

    const long l0 = (long)chunk * CL;
    const float* xsp = xs    + (long)bk * L_ * DI_ + l0 * DI_ + d;
    const float* dlp = delta + (long)bk * L_ * DI_ + l0 * DI_ + d;
    const float* bbase = xdbl + (long)bk * L_ * C44 + l0 * C44 + 12;
    float* yp = outy + (long)bk * L_ * DI_ + l0 * DI_ + d;

    float s[16];
    if (chunk == 0) {
        #pragma unroll
        for (int n = 0; n < 16; ++n) s[n] = 0.f;
    } else {
        const float* cs = carryS + (long)(chunk - 1) * NSER + ((long)bk * DI_ + d) * 16;
        #pragma unroll
        for (int q = 0; q < 4; ++q) {
            float4 v = ((const float4*)cs)[q];
            s[q*4] = v.x; s[q*4+1] = v.y; s[q*4+2] = v.z; s[q*4+3] = v.w;
        }
    }

    float dl = dlp[0], u = xsp[0];
    float4 b0 = ((const float4*)bbase)[0];
    float4 b1 = ((const float4*)bbase)[1];
    float4 b2 = ((const float4*)bbase)[2];
    float4 b3 = ((const float4*)bbase)[3];
    float4 c0 = ((const float4*)bbase)[4];   // C starts at col 28 = 12+16
    float4 c1 = ((const float4*)bbase)[5];
    float4 c2 = ((const float4*)bbase)[6];
    float4 c3 = ((const float4*)bbase)[7];

    for (int l = 0; l < CL; ++l) {
        float dln = 0.f, un = 0.f;
        float4 nb0 = {}, nb1 = {}, nb2 = {}, nb3 = {};
        float4 nc0 = {}, nc1 = {}, nc2 = {}, nc3 = {};
        if (l + 1 < CL) {
            long o = (long)(l + 1);
            dln = dlp[o * DI_]; un = xsp[o * DI_];
            const float4* Bv = (const float4*)(bbase + o * C44);
            nb0 = Bv[0]; nb1 = Bv[1]; nb2 = Bv[2]; nb3 = Bv[3];
            nc0 = Bv[4]; nc1 = Bv[5]; nc2 = Bv[6]; nc3 = Bv[7];
        }
        float B[16], Cc[16];
        *(float4*)&B[0] = b0;  *(float4*)&B[4] = b1;
        *(float4*)&B[8] = b2;  *(float4*)&B[12] = b3;
        *(float4*)&Cc[0] = c0; *(float4*)&Cc[4] = c1;
        *(float4*)&Cc[8] = c2; *(float4*)&Cc[12] = c3;
        const float du = dl * u;
        float y = Dv * u;
        #pragma unroll
        for (int n = 0; n < 16; ++n) {
            s[n] = s[n] * __expf(dl * An[n]) + du * B[n];
            y += s[n] * Cc[n];
        }
        yp[(long)l * DI_] = y;
        dl = dln; u = un;
        b0 = nb0; b1 = nb1; b2 = nb2; b3 = nb3;
        c0 = nc0; c1 = nc1; c2 = nc2; c3 = nc3;
    }
}

// ---------------------------------------------------------------------------
// Combine 4 scan directions + LayerNorm(384) + SiLU(z) gate.
// ---------------------------------------------------------------------------
__global__ __launch_bounds__(384) void combine_ln(
    const float* __restrict__ outy, const float* __restrict__ xz,
    const float* __restrict__ g, const float* __restrict__ bta,
    float* __restrict__ yln)
{
    const int bl = blockIdx.x;
    const int b = bl / L_;
    const int l = bl % L_;
    const int h = l / W_;
    const int w = l % W_;
    const int d = threadIdx.x;

    const long base = (long)b * K_ * L_ * DI_;
    const int l1 = w * H_ + h;
    float v = outy[base + 0L * L_ * DI_ + (long)l            * DI_ + d]
            + outy[base + 2L * L_ * DI_ + (long)(L_ - 1 - l) * DI_ + d]
            + outy[base + 1L * L_ * DI_ + (long)l1           * DI_ + d]
            + outy[base + 3L * L_ * DI_ + (long)(L_ - 1 - l1)* DI_ + d];

    __shared__ float red[16];
    const int lane = d & 63, wid = d >> 6;

    float s = v;
    #pragma unroll
    for (int off = 32; off; off >>= 1) s += __shfl_down(s, off, 64);
    if (lane == 0) red[wid] = s;
    __syncthreads();
    if (d == 0) {
        float t = 0.f;
        for (int i = 0; i < 6; ++i) t += red[i];
        red[8] = t * (1.f / DI_);
    }
    __syncthreads();
    const float mu = red[8];
    float dv = v - mu;
    float s2 = dv * dv;
    #pragma unroll
    for (int off = 32; off; off >>= 1) s2 += __shfl_down(s2, off, 64);
    if (lane == 0) red[wid] = s2;
    __syncthreads();
    if (d == 0) {
        float t = 0.f;
        for (int i = 0; i < 6; ++i) t += red[i];
        red[9] = t * (1.f / DI_);
    }
    __syncthreads();
    const float var = red[9];

    float z = xz[(long)bl * (2 * DI_) + DI_ + d];
    float sz = z / (1.f + __expf(-z));
    float o = dv * rsqrtf(var + 1e-5f) * g[d] + bta[d];
    yln[(long)bl * DI_ + d] = o * sz;
}

// ---------------------------------------------------------------------------
extern "C" void kernel_launch(void* const* d_in, const int* in_sizes, int n_in,
                              void* d_out, int out_size, void* d_ws, size_t ws_size,
                              hipStream_t stream)
{
    const float* x    = (const float*)d_in[0];
    const float* xt   = (const float*)d_in[1];
    const float* ipw  = (const float*)d_in[2];
    const float* c2w  = (const float*)d_in[3];
    const float* c2b  = (const float*)d_in[4];
    const float* cxw  = (const float*)d_in[5];
    const float* cxb  = (const float*)d_in[6];
    const float* xpw  = (const float*)d_in[7];
    const float* dtw  = (const float*)d_in[8];
    const float* dtb  = (const float*)d_in[9];
    const float* alog = (const float*)d_in[10];
    const float* Dsp  = (const float*)d_in[11];
    const float* ng   = (const float*)d_in[12];
    const float* nb   = (const float*)d_in[13];
    const float* opw  = (const float*)d_in[14];
    float* out = (float*)d_out;

    const size_t M = (size_t)B_ * L_;          // 9216
    float* ws = (float*)d_ws;
    float* xz    = ws;                                   // [M,768]
    float* xc    = xz    + M * (2 * DI_);                // [B,H,W,DI]
    float* xtc   = xc    + M * DI_;                      // [B,H,W,DI]
    float* xs    = xtc   + M * DI_;                      // [B,4,L,DI]
    float* xdbl  = xs    + (size_t)B_ * K_ * L_ * DI_;   // [B,4,L,44]
    float* delta = xdbl  + (size_t)B_ * K_ * L_ * C44;   // [B,4,L,DI]
    float* outy  = delta + (size_t)B_ * K_ * L_ * DI_;   // [B,4,L,DI]
    // scan carries overlay xc+xtc (dead between build_xs and combine_ln):
    // 2 * NC * NSER * 4B = 25.2 MB < 28.3 MB available.
    float* carryS = xc;                                  // [NC][NSER]
    float* carryP = carryS + (size_t)NC * NSER;
    float* yln   = xc;                                   // reused after scan

    dim3 blk(256);

    // K1: xz = x @ in_proj_w^T
    gemm_nt<0><<<dim3((int)(M / BM), (2 * DI_) / BN, 1), blk, 0, stream>>>(
        x, ipw, xz, nullptr, (int)M, 2 * DI_, DM_, DM_, DM_, 2 * DI_, 0, 0, 1, 0);

    // K2: convs + SiLU
    {
        int tot = 2 * B_ * H_ * W_ * DI_;
        conv_dw<<<(tot + 255) / 256, blk, 0, stream>>>(xz, xt, c2w, c2b, cxw, cxb, xc, xtc);
    }

    // K3: build xs
    {
        int tot = B_ * H_ * W_ * DI_;
        build_xs<<<(tot + 255) / 256, blk, 0, stream>>>(xc, xtc, xs);
    }

    // K4: x_dbl = xs @ xpw^T (batched over b,k)
    gemm_nt<0><<<dim3(L_ / BM, 1, B_ * K_), blk, 0, stream>>>(
        xs, xpw, xdbl, nullptr, L_, C44, DI_, DI_, DI_, C44,
        (long)L_ * DI_, (long)C44 * DI_, K_, (long)L_ * C44);

    // K5: delta = softplus(x_dbl[:, :12] @ dtw^T + bias)
    gemm_nt<1><<<dim3(L_ / BM, DI_ / BN, B_ * K_), blk, 0, stream>>>(
        xdbl, dtw, delta, dtb, L_, DI_, DTR_, C44, DTR_, DI_,
        (long)L_ * C44, (long)DI_ * DTR_, K_, (long)L_ * DI_);

    // K6: chunked selective scan (3 passes, register-state)
    scan_p1<<<B_ * K_ * (NC - 1), 384, 0, stream>>>(
        xs, delta, xdbl, alog, carryS, carryP);
    scan_p2<<<NSER / 256, blk, 0, stream>>>(carryS, carryP);
    scan_p3<<<B_ * K_ * NC, 384, 0, stream>>>(
        xs, delta, xdbl, alog, Dsp, carryS, outy);

    // K7: combine + LayerNorm + SiLU gate
    combine_ln<<<(int)M, 384, 0, stream>>>(outy, xz, ng, nb, yln);

    // K8: out = yln @ out_proj_w^T
    gemm_nt<0><<<dim3((int)(M / BM), DM_ / BN, 1), blk, 0, stream>>>(
        yln, opw, out, nullptr, (int)M, DM_, DI_, DI_, DI_, DM_, 0, 0, 1, 0);
}